// Round 11
// baseline (64.598 us; speedup 1.0000x reference)
//
#include <hip/hip_runtime.h>
#include <hip/hip_fp16.h>
#include <cmath>

#define NB 32
#define CH 384
#define IH 64
#define IW 64
#define OH 32
#define OW 32
#define PR 70    // padded rows 0..69; input row ri -> pr = ri+3
#define SP 35    // LDS row stride in half2 pairs (pairs 0..34 used)

typedef _Float16     h2    __attribute__((ext_vector_type(2)));
typedef unsigned int u32x4 __attribute__((ext_vector_type(4)));
typedef float        f32x4 __attribute__((ext_vector_type(4)));

__device__ __forceinline__ float fdot2(h2 a, h2 b, float c) {
#if __has_builtin(__builtin_amdgcn_fdot2)
    return __builtin_amdgcn_fdot2(a, b, c, false);
#else
    return c + (float)a.x * (float)b.x + (float)a.y * (float)b.y;
#endif
}

// ---------------------------------------------------------------------------
// Pass 1: 7x7 + 3x3 depthwise conv (stride 2), one 128-thread block per
// (n,c) plane. LDS holds the plane as fp16 column-pairs: sx[pr][p] = half2 of
// padded cols {2p, 2p+1}, padded col = orig col + 4 (so 7x7 taps for output
// ox are pairs ox..ox+3, 3x3 taps are within pairs ox+1..ox+2).
// Thread = 8-row x 1-col output strip: 21 shared rows x 4 b32 reads = 84
// conflict-free LDS reads (bank = 16*g1 + ox + i, 2 lanes/bank).
// Inner loop is v_dot2_f32_f16: 4 dot2 per 7-tap row, 2 per 3-tap row.
// Outputs packed half2{y_lk,y_sk}; per-wave stats -> partials slab (plain
// stores, every slot written every call -> no memset).
// ---------------------------------------------------------------------------
__global__ __launch_bounds__(128, 4) void conv_stats_kernel(
    const float* __restrict__ x,
    const float* __restrict__ w_lk,
    const float* __restrict__ w_sk,
    unsigned int* __restrict__ yls,  // [planes][1024] packed half2 per px
    float* __restrict__ partial)     // [CH][NB][2][4] per-wave partial sums
{
    __shared__ h2 sx[PR][SP];

    const int nc  = blockIdx.x;
    const int n   = nc / CH;
    const int c   = nc % CH;
    const int tid = threadIdx.x;

    // ---- issue all staging loads first (HBM latency hides under halo) ----
    const float4* xp4 = (const float4*)(x + (size_t)nc * (IH * IW));
    float4 vbuf[8];
#pragma unroll
    for (int it = 0; it < 8; ++it) vbuf[it] = xp4[tid + it * 128];

    h2 z2; z2.x = (_Float16)0.f; z2.y = (_Float16)0.f;

    // ---- zero halo only ----
    // rows 0,1,2 (ri -3..-1) and 67,68 (ri 64,65): all pairs
    for (int i = tid; i < 5 * SP; i += 128) {
        const int r = i / SP, q = i % SP;
        sx[(r < 3) ? r : (64 + r)][q] = z2;
    }
    // rows 3..66: side pairs 0,1 (left halo) and 34 (right halo)
    for (int i = tid; i < 64 * 3; i += 128) {
        const int r = 3 + i / 3;
        const int t = i % 3;
        sx[r][(t < 2) ? t : 34] = z2;
    }

    // ---- scatter staged registers into fp16 pairs ----
    // float4 i covers orig cols 4q4..4q4+3 -> padded 4q4+4..4q4+7
    // -> pairs 2q4+2 (x,y) and 2q4+3 (z,w); adjacent -> single b64 write.
#pragma unroll
    for (int it = 0; it < 8; ++it) {
        const int i = tid + it * 128;
        const float4 v = vbuf[it];
        const int r  = (i >> 4) + 3;
        const int q4 = i & 15;
        h2 a, b;
        a.x = (_Float16)v.x; a.y = (_Float16)v.y;
        b.x = (_Float16)v.z; b.y = (_Float16)v.w;
        sx[r][2 * q4 + 2] = a;
        sx[r][2 * q4 + 3] = b;
    }
    __syncthreads();

    // ---- weights as dot2 pairs (block-uniform) ----
    h2 pw[7][4];
#pragma unroll
    for (int ky = 0; ky < 7; ++ky) {
        const float w0 = w_lk[c * 49 + ky * 7 + 0];
        const float w1 = w_lk[c * 49 + ky * 7 + 1];
        const float w2 = w_lk[c * 49 + ky * 7 + 2];
        const float w3 = w_lk[c * 49 + ky * 7 + 3];
        const float w4 = w_lk[c * 49 + ky * 7 + 4];
        const float w5 = w_lk[c * 49 + ky * 7 + 5];
        const float w6 = w_lk[c * 49 + ky * 7 + 6];
        pw[ky][0].x = (_Float16)0.f; pw[ky][0].y = (_Float16)w0;
        pw[ky][1].x = (_Float16)w1;  pw[ky][1].y = (_Float16)w2;
        pw[ky][2].x = (_Float16)w3;  pw[ky][2].y = (_Float16)w4;
        pw[ky][3].x = (_Float16)w5;  pw[ky][3].y = (_Float16)w6;
    }
    h2 sw[3][2];
#pragma unroll
    for (int ks = 0; ks < 3; ++ks) {
        const float s0 = w_sk[c * 9 + ks * 3 + 0];
        const float s1 = w_sk[c * 9 + ks * 3 + 1];
        const float s2 = w_sk[c * 9 + ks * 3 + 2];
        sw[ks][0].x = (_Float16)0.f; sw[ks][0].y = (_Float16)s0;
        sw[ks][1].x = (_Float16)s1;  sw[ks][1].y = (_Float16)s2;
    }

    const int lane = tid & 63;
    const int wv   = tid >> 6;          // 0..1
    const int ox   = lane & 31;         // output col
    const int g1   = lane >> 5;         // 0..1
    const int r8   = g1 + 2 * wv;       // 0..3: output rows 8*r8..8*r8+7
    const int pr0  = 16 * r8;

    float accl[8] = {0.f,0.f,0.f,0.f,0.f,0.f,0.f,0.f};
    float accs[8] = {0.f,0.f,0.f,0.f,0.f,0.f,0.f,0.f};

#pragma unroll
    for (int k = 0; k <= 20; ++k) {
        const h2 L0 = sx[pr0 + k][ox];
        const h2 L1 = sx[pr0 + k][ox + 1];
        const h2 L2 = sx[pr0 + k][ox + 2];
        const h2 L3 = sx[pr0 + k][ox + 3];
#pragma unroll
        for (int j = 0; j < 8; ++j) {
            if (k >= 2 * j && k <= 2 * j + 6) {        // folds at compile time
                const int ky = k - 2 * j;
                accl[j] = fdot2(L0, pw[ky][0], accl[j]);
                accl[j] = fdot2(L1, pw[ky][1], accl[j]);
                accl[j] = fdot2(L2, pw[ky][2], accl[j]);
                accl[j] = fdot2(L3, pw[ky][3], accl[j]);
            }
            if (k >= 2 * j + 2 && k <= 2 * j + 4) {
                const int ks = k - 2 * j - 2;
                accs[j] = fdot2(L1, sw[ks][0], accs[j]);
                accs[j] = fdot2(L2, sw[ks][1], accs[j]);
            }
        }
    }

    // store packed fp16 px, accumulate per-thread stats
    float s0 = 0.f, s1 = 0.f, s2 = 0.f, s3 = 0.f;
    unsigned int* yp = yls + (size_t)nc * (OH * OW);
#pragma unroll
    for (int j = 0; j < 8; ++j) {
        const __half2 h = __floats2half2_rn(accl[j], accs[j]);
        yp[(8 * r8 + j) * OW + ox] = *reinterpret_cast<const unsigned int*>(&h);
        s0 += accl[j]; s1 += accl[j] * accl[j];
        s2 += accs[j]; s3 += accs[j] * accs[j];
    }

    // wave64 reduce, lane 0 writes this wave's partial (no atomics)
#pragma unroll
    for (int off = 32; off >= 1; off >>= 1) {
        s0 += __shfl_down(s0, off);
        s1 += __shfl_down(s1, off);
        s2 += __shfl_down(s2, off);
        s3 += __shfl_down(s3, off);
    }
    if (lane == 0) {
        ((float4*)partial)[(c * NB + n) * 2 + wv] = make_float4(s0, s1, s2, s3);
    }
}

// ---------------------------------------------------------------------------
// Pass 2: one block per (n,c) plane (256 threads = 256 uint4 = 1024 px).
// Wave 0 reduces this channel's 256 partial floats (64 lanes x float4) via
// butterfly shuffles, lane 0 folds BN -> 4 params in LDS; all threads unpack
// 4 half2 px/uint4, affine both branches, add, exact GELU.
// yls read NT (single use); out stored NT (never re-read) -> L3 kept for x.
// ---------------------------------------------------------------------------
__global__ __launch_bounds__(256) void apply_kernel(
    const u32x4* __restrict__ yls4,
    const float* __restrict__ partial,
    const float* __restrict__ gamma_lk, const float* __restrict__ beta_lk,
    const float* __restrict__ gamma_sk, const float* __restrict__ beta_sk,
    f32x4* __restrict__ out)
{
    __shared__ float sp[4];

    const int b = blockIdx.x;
    const int c = b % CH;
    const int tid = threadIdx.x;

    if (tid < 64) {
        float4 v = ((const float4*)partial)[c * 64 + tid];
        float s0 = v.x, s1 = v.y, s2 = v.z, s3 = v.w;
#pragma unroll
        for (int off = 32; off >= 1; off >>= 1) {
            s0 += __shfl_down(s0, off);
            s1 += __shfl_down(s1, off);
            s2 += __shfl_down(s2, off);
            s3 += __shfl_down(s3, off);
        }
        if (tid == 0) {
            const float inv_cnt = 1.0f / (float)(NB * OH * OW);
            const float mean_l = s0 * inv_cnt;
            const float var_l  = s1 * inv_cnt - mean_l * mean_l;
            const float sc_l   = gamma_lk[c] * rsqrtf(var_l + 1e-5f);
            const float sh_l   = beta_lk[c] - mean_l * sc_l;
            const float mean_s = s2 * inv_cnt;
            const float var_s  = s3 * inv_cnt - mean_s * mean_s;
            const float sc_s   = gamma_sk[c] * rsqrtf(var_s + 1e-5f);
            const float sh_s   = beta_sk[c] - mean_s * sc_s;
            sp[0] = sc_l; sp[1] = sh_l; sp[2] = sc_s; sp[3] = sh_s;
        }
    }
    __syncthreads();

    const float sc_l = sp[0], sh_l = sp[1], sc_s = sp[2], sh_s = sp[3];

    const int i = b * 256 + tid;
    const u32x4 v = __builtin_nontemporal_load(yls4 + i);
    const unsigned int uv0 = v.x, uv1 = v.y, uv2 = v.z, uv3 = v.w;
    const __half2 h0 = *reinterpret_cast<const __half2*>(&uv0);
    const __half2 h1 = *reinterpret_cast<const __half2*>(&uv1);
    const __half2 h2v = *reinterpret_cast<const __half2*>(&uv2);
    const __half2 h3 = *reinterpret_cast<const __half2*>(&uv3);

    const float v0 = fmaf(__low2float(h0), sc_l, sh_l) + fmaf(__high2float(h0), sc_s, sh_s);
    const float v1 = fmaf(__low2float(h1), sc_l, sh_l) + fmaf(__high2float(h1), sc_s, sh_s);
    const float v2 = fmaf(__low2float(h2v), sc_l, sh_l) + fmaf(__high2float(h2v), sc_s, sh_s);
    const float v3 = fmaf(__low2float(h3), sc_l, sh_l) + fmaf(__high2float(h3), sc_s, sh_s);

    f32x4 r;
    r.x = 0.5f * v0 * (1.0f + erff(v0 * 0.70710678118654752f));
    r.y = 0.5f * v1 * (1.0f + erff(v1 * 0.70710678118654752f));
    r.z = 0.5f * v2 * (1.0f + erff(v2 * 0.70710678118654752f));
    r.w = 0.5f * v3 * (1.0f + erff(v3 * 0.70710678118654752f));
    __builtin_nontemporal_store(r, out + i);
}

extern "C" void kernel_launch(void* const* d_in, const int* in_sizes, int n_in,
                              void* d_out, int out_size, void* d_ws, size_t ws_size,
                              hipStream_t stream) {
    const float* x        = (const float*)d_in[0];
    const float* w_lk     = (const float*)d_in[1];
    const float* gamma_lk = (const float*)d_in[2];
    const float* beta_lk  = (const float*)d_in[3];
    const float* w_sk     = (const float*)d_in[4];
    const float* gamma_sk = (const float*)d_in[5];
    const float* beta_sk  = (const float*)d_in[6];
    float* out = (float*)d_out;

    float*        partial = (float*)d_ws;                        // 393 KB
    unsigned int* yls     = (unsigned int*)(partial + CH * NB * 2 * 4); // 50 MB

    conv_stats_kernel<<<NB * CH, 128, 0, stream>>>(x, w_lk, w_sk, yls, partial);
    apply_kernel<<<NB * CH, 256, 0, stream>>>(
        (const u32x4*)yls, partial, gamma_lk, beta_lk, gamma_sk, beta_sk,
        (f32x4*)out);
}